// Round 3
// baseline (2349.154 us; speedup 1.0000x reference)
//
#include <hip/hip_runtime.h>

// HMM forward (CgpHmmCell): B=512, T=4096, S=64, M=125 — fully fused.
// One wave per sequence; lane j owns state j.
//  - x one-hot index recovered in-kernel: each lane loads 2 dwords of the
//    500 B row (software-pipelined PF=8 steps ahead -> vmcnt never drains),
//    index via 2 ballots + scalar ctz. No separate extract pass, no obs buffer.
//  - alpha@A matvec: 64x (v_readlane broadcast -> v_fmac with per-lane A col).
//  - Surrogate rescaling ONCE PER 8 STEPS by c = w[lane0] (any positive scale
//    keeps ll exact: ll = sum log c + log(sum w_final)); removes
//    readfirstlane/log2/rcp from the per-step dependency chain.
// NOTE: MASK0/MASK1 are HIP-header macros — use BALM0/BALM1.

#define BATCH 512
#define T 4096
#define S 64
#define M 125
#define PF 8  // prefetch distance == rescale period

__device__ __forceinline__ float matvec64(float a, const float (&Acol)[S]) {
    // R[j] = sum_i alpha[i] * A[i][j]; alpha broadcast lane->SGPR via readlane.
    float R0 = 0.f, R1 = 0.f, R2 = 0.f, R3 = 0.f;
    unsigned au = __float_as_uint(a);
#pragma unroll
    for (int i = 0; i < S; i += 4) {
        float s0 = __uint_as_float(__builtin_amdgcn_readlane(au, i + 0));
        float s1 = __uint_as_float(__builtin_amdgcn_readlane(au, i + 1));
        float s2 = __uint_as_float(__builtin_amdgcn_readlane(au, i + 2));
        float s3 = __uint_as_float(__builtin_amdgcn_readlane(au, i + 3));
        R0 = fmaf(s0, Acol[i + 0], R0);
        R1 = fmaf(s1, Acol[i + 1], R1);
        R2 = fmaf(s2, Acol[i + 2], R2);
        R3 = fmaf(s3, Acol[i + 3], R3);
    }
    return (R0 + R1) + (R2 + R3);
}

__global__ __launch_bounds__(64) void hmm_fused(const float* __restrict__ x,
                                                const float* __restrict__ Iv,
                                                const float* __restrict__ A,
                                                const float* __restrict__ Bm,
                                                float* __restrict__ out) {
    __shared__ float BmL[M * S];  // 32000 B; row o = Bm[o][:], stride-1 -> conflict-free
    const int lane = threadIdx.x;
    for (int i = lane; i < M * S; i += 64) BmL[i] = Bm[i];

    float Acol[S];  // column `lane` of A, in registers
#pragma unroll
    for (int i = 0; i < S; ++i) Acol[i] = A[i * S + lane];
    __syncthreads();

    const int seq = blockIdx.x;
    const float* xb = x + (size_t)seq * T * M;

    // lane covers row elements m=2*lane and m=2*lane+1; invalid lanes remapped
    // to element 0/1 (always in-bounds) and masked out of the ballots.
    const unsigned long long BALM0 = 0x7fffffffffffffffull;  // m=2*lane   <= 124
    const unsigned long long BALM1 = 0x3fffffffffffffffull;  // m=2*lane+1 <= 124
    const unsigned off0 = (2 * lane <= 124) ? (unsigned)(2 * lane) : 0u;
    const unsigned off1 = (2 * lane + 1 <= 124) ? (unsigned)(2 * lane + 1) : 1u;

    float xv0[PF], xv1[PF];
    unsigned rowoff[PF];  // wave-uniform row dword offsets (SGPRs)
#pragma unroll
    for (int k = 0; k < PF; ++k) {
        rowoff[k] = (unsigned)(k * M);
        xv0[k] = xb[rowoff[k] + off0];
        xv1[k] = xb[rowoff[k] + off1];
    }

    float a = 0.f, w = 0.f;
    double L = 0.0;

    // ---- peeled pack 0 (steps 0..7; step 0 uses I instead of the matvec) ----
#pragma unroll
    for (int k = 0; k < PF; ++k) {
        unsigned long long m0 = __ballot(xv0[k] != 0.f) & BALM0;
        unsigned long long m1 = __ballot(xv1[k] != 0.f) & BALM1;
        int o = m0 ? (int)(__builtin_ctzll(m0) << 1)
                   : (int)((__builtin_ctzll(m1) << 1) | 1);
        float E = BmL[(o << 6) + lane];
        unsigned ro = rowoff[k] + PF * M;  // reload slot k with row k+8
        rowoff[k] = ro;
        xv0[k] = xb[ro + off0];
        xv1[k] = xb[ro + off1];
        if (k == 0) {
            w = E * Iv[lane];
        } else {
            float R = matvec64(a, Acol);
            w = R * E;
        }
        a = w;
    }
    {
        float c = __uint_as_float(__builtin_amdgcn_readfirstlane(__float_as_uint(w)));
        L += (double)__log2f(c);
        a = w * __builtin_amdgcn_rcpf(c);
    }

    // ---- packs 1..511 ----
    for (int p = 1; p < T / PF; ++p) {
#pragma unroll
        for (int k = 0; k < PF; ++k) {
            unsigned long long m0 = __ballot(xv0[k] != 0.f) & BALM0;
            unsigned long long m1 = __ballot(xv1[k] != 0.f) & BALM1;
            int o = m0 ? (int)(__builtin_ctzll(m0) << 1)
                       : (int)((__builtin_ctzll(m1) << 1) | 1);
            float E = BmL[(o << 6) + lane];
            unsigned ro = rowoff[k] + PF * M;
            rowoff[k] = ro;
            unsigned lro = (ro < (unsigned)(T * M)) ? ro : 0u;  // clamp on last pack
            xv0[k] = xb[lro + off0];
            xv1[k] = xb[lro + off1];
            float R = matvec64(a, Acol);
            w = R * E;
            a = w;
        }
        // surrogate rescale once per pack; ll stays exact for any positive c
        float c = __uint_as_float(__builtin_amdgcn_readfirstlane(__float_as_uint(w)));
        L += (double)__log2f(c);
        a = w * __builtin_amdgcn_rcpf(c);
    }

    // one exact allreduce at the very end
    float s = a;
#pragma unroll
    for (int off = 32; off; off >>= 1) s += __shfl_xor(s, off);
    if (lane == 0)
        out[seq] = (float)((L + (double)__log2f(s)) * 0.6931471805599453);
}

extern "C" void kernel_launch(void* const* d_in, const int* in_sizes, int n_in,
                              void* d_out, int out_size, void* d_ws, size_t ws_size,
                              hipStream_t stream) {
    const float* x  = (const float*)d_in[0];   // [B,T,M] one-hot
    const float* I  = (const float*)d_in[1];   // [1,S]
    const float* A  = (const float*)d_in[2];   // [S,S]
    const float* Bm = (const float*)d_in[3];   // [M,S]
    float* out = (float*)d_out;                // [B,1]
    (void)d_ws; (void)ws_size;

    hmm_fused<<<BATCH, 64, 0, stream>>>(x, I, A, Bm, out);
}

// Round 5
// 1624.780 us; speedup vs baseline: 1.4458x; 1.4458x over previous
//
#include <hip/hip_runtime.h>

// HMM forward (CgpHmmCell): B=512, T=4096, S=64, M=125.
// Round 5: overlap-save time-chunking (Round-4 structure) with two fixes:
//  (1) burn-in carry seeded a=1.0 (was 0.0 -> 0*inf=NaN on first rescale);
//  (2) surrogate scale clamped to >=1e-30 so rcp can never see 0.
// Each of NCHUNK=8 chunks per sequence burns in BURN=48 steps from the
// preceding window (chunk 0 starts exactly); its ll contribution is EXACT
// via the mass identity  dL = sum log c_t + log(sum a_end) - log(sum a_start)
// for ANY positive scales c. Contributions combine with atomicAdd.
// => 4096 waves: ~16 waves/CU, latency hidden (Round 3 had 0.5 waves/SIMD).
// Per wave: lane j owns state j; matvec via 64x readlane-broadcast fmac;
// one-hot index recovered by 2 ballots (rows prefetched PF=8 ahead);
// surrogate rescale once per 8 steps.
// NOTE: MASK0/MASK1 are HIP-header macros — use BALM0/BALM1.

#define BATCH 512
#define T 4096
#define S 64
#define M 125
#define PF 8
#define NCHUNK 8
#define CHUNKLEN (T / NCHUNK)  // 512
#define BURN 48                // 6 packs of burn-in
#define WPB 4                  // waves per block (share one BmL tile)

#define BALM0 0x7fffffffffffffffull  // lanes with m=2*lane   <= 124
#define BALM1 0x3fffffffffffffffull  // lanes with m=2*lane+1 <= 124

__device__ __forceinline__ float matvec64(float a, const float (&Acol)[S]) {
    float R0 = 0.f, R1 = 0.f, R2 = 0.f, R3 = 0.f;
    unsigned au = __float_as_uint(a);
#pragma unroll
    for (int i = 0; i < S; i += 4) {
        float s0 = __uint_as_float(__builtin_amdgcn_readlane(au, i + 0));
        float s1 = __uint_as_float(__builtin_amdgcn_readlane(au, i + 1));
        float s2 = __uint_as_float(__builtin_amdgcn_readlane(au, i + 2));
        float s3 = __uint_as_float(__builtin_amdgcn_readlane(au, i + 3));
        R0 = fmaf(s0, Acol[i + 0], R0);
        R1 = fmaf(s1, Acol[i + 1], R1);
        R2 = fmaf(s2, Acol[i + 2], R2);
        R3 = fmaf(s3, Acol[i + 3], R3);
    }
    return (R0 + R1) + (R2 + R3);
}

__device__ __forceinline__ void reload(const float* __restrict__ xb,
                                       float (&xv0)[PF], float (&xv1)[PF],
                                       unsigned (&rowoff)[PF], int k,
                                       unsigned off0, unsigned off1) {
    unsigned ro = rowoff[k] + PF * M;       // wave-uniform (SGPR) row offset
    rowoff[k] = ro;
    unsigned lro = (ro < (unsigned)(T * M)) ? ro : 0u;  // clamp past seq end
    xv0[k] = xb[lro + off0];
    xv1[k] = xb[lro + off1];
}

template <bool ACC>
__device__ __forceinline__ void run_pack(const float* __restrict__ xb,
                                         float (&xv0)[PF], float (&xv1)[PF],
                                         unsigned (&rowoff)[PF],
                                         unsigned off0, unsigned off1, int lane,
                                         const float (&Acol)[S],
                                         const float* __restrict__ BmL,
                                         float& a, double& L) {
#pragma unroll
    for (int k = 0; k < PF; ++k) {
        unsigned long long m0 = __ballot(xv0[k] != 0.f) & BALM0;
        unsigned long long m1 = __ballot(xv1[k] != 0.f) & BALM1;
        int o = m0 ? (int)(__builtin_ctzll(m0) << 1)
                   : (int)((__builtin_ctzll(m1) << 1) | 1);
        float E = BmL[(o << 6) + lane];
        reload(xb, xv0, xv1, rowoff, k, off0, off1);
        a = matvec64(a, Acol) * E;
    }
    float c = __uint_as_float(__builtin_amdgcn_readfirstlane(__float_as_uint(a)));
    c = fmaxf(c, 1e-30f);  // never let rcp see 0/denormal
    if (ACC) L += (double)__log2f(c);
    a *= __builtin_amdgcn_rcpf(c);
}

__device__ __forceinline__ float wave_sum(float v) {
#pragma unroll
    for (int off = 32; off; off >>= 1) v += __shfl_xor(v, off);
    return v;
}

__global__ __launch_bounds__(256) void hmm_chunked(const float* __restrict__ x,
                                                   const float* __restrict__ Iv,
                                                   const float* __restrict__ A,
                                                   const float* __restrict__ Bm,
                                                   float* __restrict__ out) {
    __shared__ float BmL[M * S];  // 32000 B shared by 4 waves
    const int tid = threadIdx.x, lane = tid & 63, wv = tid >> 6;
    for (int i = tid; i < M * S; i += 256) BmL[i] = Bm[i];

    float Acol[S];  // column `lane` of A, in registers
#pragma unroll
    for (int i = 0; i < S; ++i) Acol[i] = A[i * S + lane];
    __syncthreads();

    const int g = blockIdx.x * WPB + wv;  // global wave id, 0..4095
    const int seq = g >> 3, chunk = g & (NCHUNK - 1);
    const float* xb = x + (size_t)seq * T * M;

    // lane covers row elements m=2*lane, 2*lane+1; invalid lanes remapped to
    // always-in-bounds element 0/1 and masked out of the ballots.
    const unsigned off0 = (2 * lane <= 124) ? (unsigned)(2 * lane) : 0u;
    const unsigned off1 = (2 * lane + 1 <= 124) ? (unsigned)(2 * lane + 1) : 1u;

    const int trow0 = (chunk == 0) ? 0 : chunk * CHUNKLEN - BURN;
    float xv0[PF], xv1[PF];
    unsigned rowoff[PF];
#pragma unroll
    for (int k = 0; k < PF; ++k) {
        rowoff[k] = (unsigned)((trow0 + k) * M);
        xv0[k] = xb[rowoff[k] + off0];
        xv1[k] = xb[rowoff[k] + off1];
    }

    float a = 1.0f;  // FIX: positive seed for burn-in (was 0 -> NaN)
    double L = 0.0;

    if (chunk == 0) {
        // peeled first pack: step 0 uses the initial distribution I
#pragma unroll
        for (int k = 0; k < PF; ++k) {
            unsigned long long m0 = __ballot(xv0[k] != 0.f) & BALM0;
            unsigned long long m1 = __ballot(xv1[k] != 0.f) & BALM1;
            int o = m0 ? (int)(__builtin_ctzll(m0) << 1)
                       : (int)((__builtin_ctzll(m1) << 1) | 1);
            float E = BmL[(o << 6) + lane];
            reload(xb, xv0, xv1, rowoff, k, off0, off1);
            a = (k == 0) ? E * Iv[lane] : matvec64(a, Acol) * E;
        }
        float c = __uint_as_float(__builtin_amdgcn_readfirstlane(__float_as_uint(a)));
        c = fmaxf(c, 1e-30f);
        L += (double)__log2f(c);
        a *= __builtin_amdgcn_rcpf(c);
        for (int p = 1; p < CHUNKLEN / PF; ++p)
            run_pack<true>(xb, xv0, xv1, rowoff, off0, off1, lane, Acol, BmL, a, L);
    } else {
        // burn-in: converge alpha direction, no ll accumulation
        for (int p = 0; p < BURN / PF; ++p)
            run_pack<false>(xb, xv0, xv1, rowoff, off0, off1, lane, Acol, BmL, a, L);
        // mass baseline at chunk start (exact identity, no normalize needed)
        L = -(double)__log2f(wave_sum(a));
        for (int p = 0; p < CHUNKLEN / PF; ++p)
            run_pack<true>(xb, xv0, xv1, rowoff, off0, off1, lane, Acol, BmL, a, L);
    }

    L += (double)__log2f(wave_sum(a));
    if (lane == 0)
        atomicAdd(out + seq, (float)(L * 0.6931471805599453));
}

extern "C" void kernel_launch(void* const* d_in, const int* in_sizes, int n_in,
                              void* d_out, int out_size, void* d_ws, size_t ws_size,
                              hipStream_t stream) {
    const float* x  = (const float*)d_in[0];   // [B,T,M] one-hot
    const float* I  = (const float*)d_in[1];   // [1,S]
    const float* A  = (const float*)d_in[2];   // [S,S]
    const float* Bm = (const float*)d_in[3];   // [M,S]
    float* out = (float*)d_out;                // [B,1]
    (void)d_ws; (void)ws_size;

    hipMemsetAsync(out, 0, (size_t)out_size * sizeof(float), stream);
    hmm_chunked<<<(BATCH * NCHUNK) / WPB, WPB * 64, 0, stream>>>(x, I, A, Bm, out);
}

// Round 6
// 1347.413 us; speedup vs baseline: 1.7435x; 1.2059x over previous
//
#include <hip/hip_runtime.h>

// HMM forward (CgpHmmCell): B=512, T=4096, S=64, M=125.
// Round 6: MFMA-batched scan. Phase 1 recovers obs bytes (HBM-floor linear
// read). Phase 2: each wave advances 16 chunk-streams at once:
//   alphaT [state,strm] is the MFMA B operand; A^T lives as 8 constant
//   16x16x32 bf16 A-fragments in registers; D = A^T @ alphaT lands in C
//   layout where each lane owns ONE stream (col = lane&15), so emission
//   multiply / surrogate rescale / log-accum are per-lane. Per-step C->B
//   layout transpose via padded per-wave LDS scratch (packed bf16 pairs).
// Overlap-save: NCHUNK=32 chunks/seq, BURN=48; chunk 0 gets an exact I*E0
// override at its boundary; contribution = S1 - S0 via the mass identity
// (surrogate scales cancel exactly). atomicAdd per stream into out.

#define BATCH 512
#define T 4096
#define S 64
#define M 125
#define NPACK 22   // 6 burn packs + 16 acc packs, 8 steps each = 176 steps
#define WPB 4
#define BSTR 68    // BmL row stride in floats (padded: breaks o*64 bank alias)
#define WSTR 17    // w-scratch row stride in u32 (padded)

typedef __attribute__((ext_vector_type(8))) short bf16x8;
typedef __attribute__((ext_vector_type(4))) float f32x4;

union BFU { unsigned u[4]; bf16x8 v; };

__device__ __forceinline__ unsigned pk_bf16(float a, float b) {
    unsigned ua = __float_as_uint(a) + 0x8000u;   // round-half-up to bf16
    unsigned ub = __float_as_uint(b) + 0x8000u;
    return (ub & 0xFFFF0000u) | (ua >> 16);
}
__device__ __forceinline__ unsigned pk_bf16_rne(float a, float b) {
    unsigned ua = __float_as_uint(a); ua += 0x7FFFu + ((ua >> 16) & 1u);
    unsigned ub = __float_as_uint(b); ub += 0x7FFFu + ((ub >> 16) & 1u);
    return (ub & 0xFFFF0000u) | (ua >> 16);
}

// ---------------- Phase 1: one-hot -> byte index (HBM-floor) ----------------
__global__ __launch_bounds__(256) void extract_obs(const float4* __restrict__ x4,
                                                   unsigned char* __restrict__ obs) {
    const long long n4 = (long long)BATCH * T * M / 4;
    long long stride = (long long)gridDim.x * blockDim.x;
    for (long long i = (long long)blockIdx.x * blockDim.x + threadIdx.x; i < n4; i += stride) {
        float4 v = x4[i];
        if (v.x != 0.0f || v.y != 0.0f || v.z != 0.0f || v.w != 0.0f) {
            long long e = i * 4;
            if (v.x != 0.0f) { long long r = (e + 0) / M; obs[r] = (unsigned char)(e + 0 - r * M); }
            if (v.y != 0.0f) { long long r = (e + 1) / M; obs[r] = (unsigned char)(e + 1 - r * M); }
            if (v.z != 0.0f) { long long r = (e + 2) / M; obs[r] = (unsigned char)(e + 2 - r * M); }
            if (v.w != 0.0f) { long long r = (e + 3) / M; obs[r] = (unsigned char)(e + 3 - r * M); }
        }
    }
}

// ---------------- Phase 2: MFMA scan, 16 streams per wave ----------------
__global__ __launch_bounds__(256) void hmm_mfma(const unsigned char* __restrict__ obs,
                                                const float* __restrict__ Iv,
                                                const float* __restrict__ A,
                                                const float* __restrict__ Bm,
                                                float* __restrict__ out) {
    __shared__ __align__(16) float BmL[M * BSTR];        // 34000 B
    __shared__ __align__(16) float ILds[S];
    __shared__ unsigned wscAll[WPB][32 * WSTR];          // per-wave transpose scratch

    const int tid = threadIdx.x, wv = tid >> 6, lane = tid & 63;
    const int s = lane & 15, g = lane >> 4;

    for (int i = tid; i < M * S; i += 256) BmL[(i >> 6) * BSTR + (i & 63)] = Bm[i];
    if (tid < S) ILds[tid] = Iv[tid];
    __syncthreads();

    // Constant A-fragments: Aop[m][k] = A[k_global][m_global] (i.e. A^T).
    // Lane l: m = 16*mt + (l&15), k = 32*kf + 8*g + j.
    BFU Af[4][2];
#pragma unroll
    for (int mt = 0; mt < 4; ++mt)
#pragma unroll
        for (int kf = 0; kf < 2; ++kf)
#pragma unroll
            for (int j2 = 0; j2 < 4; ++j2) {
                int k0 = kf * 32 + g * 8 + 2 * j2;
                float f0 = A[(size_t)k0 * S + mt * 16 + s];
                float f1 = A[(size_t)(k0 + 1) * S + mt * 16 + s];
                Af[mt][kf].u[j2] = pk_bf16_rne(f0, f1);
            }

    f32x4 I4[4];  // I[16*mt + 4*g + r] for the chunk-0 override
#pragma unroll
    for (int mt = 0; mt < 4; ++mt) I4[mt] = *(const f32x4*)&ILds[mt * 16 + g * 4];

    const int W = blockIdx.x * WPB + wv;      // 0..1023
    const int seq = W >> 1, hw = W & 1;
    const int chunk = hw * 16 + s;            // this lane's stream
    const bool c0wave = (hw == 0);
    const bool is_c0 = c0wave && (s == 0);

    const unsigned long long* orow = (const unsigned long long*)(obs + (size_t)seq * T);
    const int idx0 = chunk * 16 - 6;          // (128*chunk - 48) / 8

    unsigned* wsc = wscAll[wv];

    BFU Bf[2];                                // alphaT bf16 fragments, init = 1.0
#pragma unroll
    for (int kf = 0; kf < 2; ++kf)
#pragma unroll
        for (int j = 0; j < 4; ++j) Bf[kf].u[j] = 0x3F803F80u;

    float w[4][4];
    float Ls = 0.f, S0v = 0.f, c = 1.f;

    int i0 = idx0 < 0 ? 0 : idx0;
    unsigned long long u = orow[i0];

    for (int p = 0; p < NPACK; ++p) {
        int in_ = idx0 + p + 1;
        in_ = in_ < 0 ? 0 : (in_ > T / 8 - 1 ? T / 8 - 1 : in_);
        unsigned long long un = orow[in_];    // prefetch next pack
        const bool ovp = c0wave && (p == 6);  // chunk-0 exact-init pack
#pragma unroll
        for (int k = 0; k < 8; ++k) {
            const int o = (int)((u >> (8 * k)) & 255ull);
            f32x4 E[4];
#pragma unroll
            for (int mt = 0; mt < 4; ++mt)
                E[mt] = *(const f32x4*)&BmL[o * BSTR + mt * 16 + g * 4];
            f32x4 acc[4];
#pragma unroll
            for (int mt = 0; mt < 4; ++mt) {
                f32x4 z = {0.f, 0.f, 0.f, 0.f};
                z = __builtin_amdgcn_mfma_f32_16x16x32_bf16(Af[mt][0].v, Bf[0].v, z, 0, 0, 0);
                acc[mt] = __builtin_amdgcn_mfma_f32_16x16x32_bf16(Af[mt][1].v, Bf[1].v, z, 0, 0, 0);
            }
#pragma unroll
            for (int mt = 0; mt < 4; ++mt)
#pragma unroll
                for (int r = 0; r < 4; ++r) {
                    float wv_ = acc[mt][r] * E[mt][r];
                    if (ovp && k == 0)        // exact init of chunk 0 at t=0
                        wv_ = is_c0 ? I4[mt][r] * E[mt][r] : wv_;
                    w[mt][r] = wv_;
                }
            float scale = 1.f;
            if (k == 7) {                     // per-pack surrogate rescale
                c = __uint_as_float(__builtin_amdgcn_ds_bpermute(s << 2, __float_as_uint(w[0][0])));
                c = fmaxf(c, 1e-37f);
                Ls += __log2f(c);
                scale = __builtin_amdgcn_rcpf(c);
            }
            // C-layout -> B-layout transpose via LDS (packed bf16 pairs)
#pragma unroll
            for (int mt = 0; mt < 4; ++mt)
#pragma unroll
                for (int pr = 0; pr < 2; ++pr) {
                    float v0 = w[mt][2 * pr], v1 = w[mt][2 * pr + 1];
                    if (k == 7) { v0 *= scale; v1 *= scale; }
                    wsc[(2 * g + pr + 8 * mt) * WSTR + s] = pk_bf16(v0, v1);
                }
#pragma unroll
            for (int kf = 0; kf < 2; ++kf)
#pragma unroll
                for (int j = 0; j < 4; ++j)
                    Bf[kf].u[j] = wsc[(4 * g + j + 16 * kf) * WSTR + s];
        }
        if (p == 5) {  // burn/acc boundary: mass baseline S0
            float sw = 0.f;
#pragma unroll
            for (int mt = 0; mt < 4; ++mt)
#pragma unroll
                for (int r = 0; r < 4; ++r) sw += w[mt][r];
            sw += __shfl_xor(sw, 16);
            sw += __shfl_xor(sw, 32);
            S0v = (chunk == 0) ? Ls : (Ls + __log2f(sw) - __log2f(c));
        }
        u = un;
    }

    float sw = 0.f;
#pragma unroll
    for (int mt = 0; mt < 4; ++mt)
#pragma unroll
        for (int r = 0; r < 4; ++r) sw += w[mt][r];
    sw += __shfl_xor(sw, 16);
    sw += __shfl_xor(sw, 32);
    float Lfin = Ls + __log2f(sw) - __log2f(c) - S0v;
    if (lane < 16)
        atomicAdd(out + seq, Lfin * 0.6931471805599453f);
}

extern "C" void kernel_launch(void* const* d_in, const int* in_sizes, int n_in,
                              void* d_out, int out_size, void* d_ws, size_t ws_size,
                              hipStream_t stream) {
    const float* x  = (const float*)d_in[0];   // [B,T,M] one-hot
    const float* I  = (const float*)d_in[1];   // [1,S]
    const float* A  = (const float*)d_in[2];   // [S,S]
    const float* Bm = (const float*)d_in[3];   // [M,S]
    float* out = (float*)d_out;                // [B,1]
    unsigned char* obs = (unsigned char*)d_ws; // B*T = 2 MB of uint8

    hipMemsetAsync(out, 0, (size_t)out_size * sizeof(float), stream);
    extract_obs<<<65536, 256, 0, stream>>>((const float4*)x, obs);
    hmm_mfma<<<256, WPB * 64, 0, stream>>>(obs, I, A, Bm, out);  // 1024 waves
}